// Round 6
// baseline (228.869 us; speedup 1.0000x reference)
//
#include <hip/hip_runtime.h>
#include <hip/hip_bf16.h>

// Problem: B=16, C=512, H=W=64 -> HW=4096, fp32.
// attn[b,c,d] = sum_n q[b,c,n]*kv[b,d,n]; P = softmax_d(attn);
// info[b,c,n] = sum_d P[b,c,d]*kv[b,d,n]; out = gamma*info + img.
//
// R6 structure:
//   prep_kv: txt f32 -> kv16 bf16 (in d_out) + kvT bf16 (in ws)
//   gemm_qk: attn partials = img(f32) * kv16^T; 2-deep pipeline (A regs
//            ping-pong, B triple-buffered LDS, counted vmcnt(6)) SPLITK=2
//   softmax: partial-sum + row softmax -> P bf16 (ws)
//   gemm_pv: out = gamma*(kvT * P^T) + img; m97 single-buffer, k-loop fully
//            unrolled with img reads spread 1 f32x4/step (epilogue = store only)

constexpr int NB = 16;
constexpr int NC = 512;
constexpr int NHW = 4096;
constexpr int QKSPLIT = 2;

typedef float f32x4 __attribute__((ext_vector_type(4)));
typedef __bf16 bf16x4 __attribute__((ext_vector_type(4)));
typedef __bf16 bf16x8 __attribute__((ext_vector_type(8)));

__device__ __forceinline__ void gload16(const void* g, void* l) {
  __builtin_amdgcn_global_load_lds(
      (const __attribute__((address_space(1))) void*)g,
      (__attribute__((address_space(3))) void*)l, 16, 0, 0);
}

// ---------------------------------------------------------------------------
// gemm_qk: D[m][n'] = sum_k A[m][k]*B[n'][k], A f32 (img), B bf16 (kv16).
// Tile 128x128, BK=64, 8 waves (2Mx4N), wave tile 64x32.
// 2-deep software pipeline, stall-free steady state:
//   iter tt: issue loadA(t+2)[4 vmem] + stageB(t+2)[2 vmem]; compute(t);
//   barrier; vmcnt(6) -> drains A(t+1),B(t+1) (issued a full iter ago);
//   writeA(t+1); lgkmcnt(0); barrier.
// sA double (2x16K), sB triple (3x16K) = 80 KiB -> 2 blocks/CU (same as R5).
// ---------------------------------------------------------------------------
template <int SPLITS>
__global__ __launch_bounds__(512) void gemm_qk(const float* __restrict__ Af,
                                               const __bf16* __restrict__ B,
                                               float* __restrict__ Dp) {
  __shared__ __bf16 sA[2][128 * 64];
  __shared__ __bf16 sB[3][128 * 64];

  const int t = threadIdx.x;
  const int lane = t & 63;
  const int wave = t >> 6;
  const int wr = wave >> 2;
  const int wc = wave & 3;

  // XCD-aware remap (NWG % 8 == 0): XCD j gets a contiguous tile chunk.
  constexpr int NWG = 16 * NB * SPLITS;
  constexpr int QX = NWG / 8;
  int flat = blockIdx.x + 4 * (blockIdx.y + 4 * blockIdx.z);
  flat = (flat & 7) * QX + (flat >> 3);
  const int bx = flat & 3;
  const int by = (flat >> 2) & 3;
  const int bz = flat >> 4;
  const int batch = bz / SPLITS;
  const int split = bz % SPLITS;

  const int aRow0 = bx * 128;
  const int bRow0 = by * 128;
  constexpr int KSUB = NHW / SPLITS;
  constexpr int NT = KSUB / 64;  // 32 (even)
  const int kBeg = split * KSUB;

  // B staging (gload_lds): rows wave*16 + i*8 + (lane>>3), src chunk XOR
  const int rl = lane >> 3;
  const int csrc = ((lane & 7) ^ rl) * 8;
  const __bf16* Bbase = B + (long)batch * NC * NHW +
                        (long)(bRow0 + wave * 16 + rl) * NHW + csrc + kBeg;
  const int ldsOff = wave * 16 * 64;

  // A staging (f32 regs): k-cols c4..c4+3, rows rb + 32*i
  const int c4 = (t & 15) * 4;
  const int rb = t >> 4;
  const float* Abase =
      Af + (long)batch * NC * NHW + (long)(aRow0 + rb) * NHW + kBeg + c4;

  auto loadA = [&](f32x4 (&ra)[4], int kof) {
#pragma unroll
    for (int i = 0; i < 4; ++i)
      ra[i] = *(const f32x4*)(Abase + kof + (long)(32 * i) * NHW);
  };
  auto writeA = [&](int buf, const f32x4 (&ra)[4]) {
#pragma unroll
    for (int i = 0; i < 4; ++i) {
      const int r = rb + 32 * i;
      const int idx = r * 64 + (c4 ^ ((r & 7) << 3));
      bf16x4 h = {(__bf16)ra[i].x, (__bf16)ra[i].y, (__bf16)ra[i].z,
                  (__bf16)ra[i].w};
      *(bf16x4*)&sA[buf][idx] = h;
    }
  };
  auto stageB = [&](int buf, int kof) {
#pragma unroll
    for (int i = 0; i < 2; ++i)
      gload16(Bbase + kof + (long)(i * 8) * NHW, &sB[buf][ldsOff + i * 8 * 64]);
  };

  f32x4 acc[4][2] = {};
  auto compute_tile = [&](int bufA, int bufB) {
#pragma unroll
    for (int kk = 0; kk < 2; ++kk) {
      const int kb = kk * 32 + ((lane >> 4) << 3);
      bf16x8 af[4], bfr[2];
#pragma unroll
      for (int m = 0; m < 4; ++m) {
        const int r = wr * 64 + m * 16 + (lane & 15);
        af[m] = *(const bf16x8*)&sA[bufA][r * 64 + (kb ^ ((r & 7) << 3))];
      }
#pragma unroll
      for (int n = 0; n < 2; ++n) {
        const int r = wc * 32 + n * 16 + (lane & 15);
        bfr[n] = *(const bf16x8*)&sB[bufB][r * 64 + (kb ^ ((r & 7) << 3))];
      }
#pragma unroll
      for (int m = 0; m < 4; ++m)
#pragma unroll
        for (int n = 0; n < 2; ++n)
          acc[m][n] = __builtin_amdgcn_mfma_f32_16x16x32_bf16(
              af[m], bfr[n], acc[m][n], 0, 0, 0);
    }
  };

  f32x4 raE[4], raO[4];  // A-reg ping-pong (named sets: no runtime indexing)

  // ---- prologue: A(0)->sA[0] now; A(1),B(1) left in flight (6 vmem) ----
  loadA(raE, 0);     // A(0), 4 vmem
  stageB(0, 0);      // B(0), 2 vmem
  loadA(raO, 64);    // A(1), 4 vmem
  stageB(1, 64);     // B(1), 2 vmem
  asm volatile("s_waitcnt vmcnt(6)" ::: "memory");  // A(0),B(0) landed
  writeA(0, raE);
  asm volatile("s_waitcnt lgkmcnt(0)" ::: "memory");
  __builtin_amdgcn_s_barrier();

  // ---- steady loop; raNext receives A(t+2), raCur holds A(t+1) ----
  auto body = [&](int tt, f32x4 (&raNext)[4], const f32x4 (&raCur)[4]) {
    const bool deep = (tt + 2) < NT;
    if (deep) {
      loadA(raNext, (tt + 2) * 64);   // 4 vmem
      stageB((tt + 2) % 3, (tt + 2) * 64);  // 2 vmem
    }
    compute_tile(tt & 1, tt % 3);
    __builtin_amdgcn_s_barrier();  // all waves done reading bufs of tt
    if (tt + 1 < NT) {
      if (deep)
        asm volatile("s_waitcnt vmcnt(6)" ::: "memory");  // A,B(t+1) landed
      else
        asm volatile("s_waitcnt vmcnt(0)" ::: "memory");
      writeA((tt + 1) & 1, raCur);
      asm volatile("s_waitcnt lgkmcnt(0)" ::: "memory");
      __builtin_amdgcn_s_barrier();
    }
  };
#pragma unroll 1
  for (int d = 0; d < NT / 2; ++d) {
    body(2 * d, raE, raO);      // loads A(2d+2) into raE; writes A(2d+1)=raO
    body(2 * d + 1, raO, raE);  // loads A(2d+3) into raO; writes A(2d+2)=raE
  }

  // epilogue: partial store. C/D layout: col=lane&15, row=(lane>>4)*4+reg
  float* D = Dp + ((long)split * NB + batch) * NC * NC;
  const int m0 = aRow0 + wr * 64;
  const int n0 = bRow0 + wc * 32;
#pragma unroll
  for (int m = 0; m < 4; ++m)
#pragma unroll
    for (int n = 0; n < 2; ++n) {
      const int row0 = m0 + m * 16 + ((lane >> 4) << 2);
      const int col = n0 + n * 16 + (lane & 15);
#pragma unroll
      for (int r = 0; r < 4; ++r)
        D[(long)(row0 + r) * NC + col] = acc[m][n][r];
    }
}

// ---------------------------------------------------------------------------
// gemm_pv: out[b][c][sp] = gamma * sum_d kvT[sp][d]*P[c][d] + img[b][c][sp].
// m97 single-buffer structure; k-loop FULLY UNROLLED (8 steps) with one img
// f32x4 load issued per step -> the 268 MB img/out traffic is spread across
// the loop and the epilogue is compute+store only.
// ---------------------------------------------------------------------------
__global__ __launch_bounds__(512) void gemm_pv(const __bf16* __restrict__ A,
                                               const __bf16* __restrict__ B,
                                               const float* __restrict__ img,
                                               const float* __restrict__ gammap,
                                               float* __restrict__ outp) {
  __shared__ __bf16 sA[128 * 64];
  __shared__ __bf16 sB[128 * 64];

  const int t = threadIdx.x;
  const int lane = t & 63;
  const int wave = t >> 6;
  const int wr = wave >> 2;
  const int wc = wave & 3;

  constexpr int GX = NHW / 128;     // 32
  constexpr int NWG = GX * 4 * NB;  // 2048
  constexpr int QX = NWG / 8;
  int flat = blockIdx.x + GX * (blockIdx.y + 4 * blockIdx.z);
  flat = (flat & 7) * QX + (flat >> 3);
  const int bx = flat % GX;
  const int by = (flat / GX) & 3;
  const int batch = flat / (GX * 4);

  const int aRow0 = bx * 128;
  const int bRow0 = by * 128;

  const int rl = lane >> 3;
  const int csrc = ((lane & 7) ^ rl) * 8;
  const __bf16* Abase =
      A + (long)batch * NHW * NC + (long)(aRow0 + wave * 16 + rl) * NC + csrc;
  const __bf16* Bbase =
      B + (long)batch * NC * NC + (long)(bRow0 + wave * 16 + rl) * NC + csrc;
  const int ldsOff = wave * 16 * 64;

  // epilogue coordinates (also used for spread img loads)
  const long obase = (long)batch * NC * NHW;
  const int sp0 = aRow0 + wr * 64;
  const int ch0 = bRow0 + wc * 32;

  f32x4 acc[4][2] = {};
  f32x4 iv[8];  // img values, loaded one per k-step (static indexing)

#pragma unroll
  for (int step = 0; step < 8; ++step) {
    const int k0 = step * 64;
#pragma unroll
    for (int i = 0; i < 2; ++i) {
      gload16(Abase + k0 + (long)(i * 8) * NC, &sA[ldsOff + i * 8 * 64]);
      gload16(Bbase + k0 + (long)(i * 8) * NC, &sB[ldsOff + i * 8 * 64]);
    }
    {  // spread img read: tile (m,n) = (step>>1, step&1)
      const int m = step >> 1, n = step & 1;
      const int sp = sp0 + m * 16 + ((lane >> 4) << 2);
      const int ch = ch0 + n * 16 + (lane & 15);
      iv[step] = *(const f32x4*)(img + obase + (long)ch * NHW + sp);
    }
    __syncthreads();  // drains vmcnt (gload_lds + img) — m97 structure
#pragma unroll
    for (int kk = 0; kk < 2; ++kk) {
      const int kb = kk * 32 + ((lane >> 4) << 3);
      bf16x8 af[4], bfr[2];
#pragma unroll
      for (int m = 0; m < 4; ++m) {
        const int r = wr * 64 + m * 16 + (lane & 15);
        af[m] = *(const bf16x8*)&sA[r * 64 + (kb ^ ((r & 7) << 3))];
      }
#pragma unroll
      for (int n = 0; n < 2; ++n) {
        const int r = wc * 32 + n * 16 + (lane & 15);
        bfr[n] = *(const bf16x8*)&sB[r * 64 + (kb ^ ((r & 7) << 3))];
      }
#pragma unroll
      for (int m = 0; m < 4; ++m)
#pragma unroll
        for (int n = 0; n < 2; ++n)
          acc[m][n] = __builtin_amdgcn_mfma_f32_16x16x32_bf16(
              af[m], bfr[n], acc[m][n], 0, 0, 0);
    }
    __syncthreads();
  }

  // epilogue: store only
  const float g = gammap[0];
#pragma unroll
  for (int m = 0; m < 4; ++m)
#pragma unroll
    for (int n = 0; n < 2; ++n) {
      const int sp = sp0 + m * 16 + ((lane >> 4) << 2);
      const int ch = ch0 + n * 16 + (lane & 15);
      const long idx = obase + (long)ch * NHW + sp;
      f32x4 ov;
#pragma unroll
      for (int r = 0; r < 4; ++r) ov[r] = g * acc[m][n][r] + iv[m * 2 + n][r];
      *(f32x4*)(outp + idx) = ov;
    }
}

// ---------------------------------------------------------------------------
// prep_kv: kv[b][d][n] f32 -> kv16[b][d][n] bf16 AND kvT[b][n][d] bf16.
// ---------------------------------------------------------------------------
__global__ __launch_bounds__(256) void prep_kv(const float* __restrict__ kv,
                                               __bf16* __restrict__ kv16,
                                               __bf16* __restrict__ kvT) {
  __shared__ __bf16 tile[64 * 68];
  const int t = threadIdx.x;
  const int n0 = blockIdx.x * 64;
  const int d0 = blockIdx.y * 64;
  const long ibase = (long)blockIdx.z * NC * NHW;

  const int nc4 = (t & 15) * 4;
  const int dr0 = t >> 4;
#pragma unroll
  for (int i = 0; i < 4; ++i) {
    const int dr = dr0 + 16 * i;
    f32x4 v = *(const f32x4*)(kv + ibase + (long)(d0 + dr) * NHW + n0 + nc4);
    bf16x4 h = {(__bf16)v.x, (__bf16)v.y, (__bf16)v.z, (__bf16)v.w};
    *(bf16x4*)&tile[dr * 68 + nc4] = h;
    *(bf16x4*)(kv16 + ibase + (long)(d0 + dr) * NHW + n0 + nc4) = h;
  }
  __syncthreads();

  const long obase = (long)blockIdx.z * NHW * NC;
  const int nr = t >> 2;
  const int dc0 = t & 3;
#pragma unroll
  for (int i = 0; i < 2; ++i) {
    const int dc = dc0 + 4 * i;
    bf16x8 pk;
#pragma unroll
    for (int j = 0; j < 8; ++j) pk[j] = tile[(dc * 8 + j) * 68 + nr];
    *(bf16x8*)(kvT + obase + (long)(n0 + nr) * NC + d0 + dc * 8) = pk;
  }
}

// ---------------------------------------------------------------------------
// Row softmax with split-K reduction -> P bf16. One wave per row.
// ---------------------------------------------------------------------------
template <int SPLITS>
__global__ __launch_bounds__(256) void softmax_rows(
    const float* __restrict__ attn, __bf16* __restrict__ P) {
  const int row = blockIdx.x * 4 + (threadIdx.x >> 6);
  const int lane = threadIdx.x & 63;
  const long PS = (long)NB * NC * NC;
  const float* src = attn + (long)row * NC;

  float x[8] = {0.f, 0.f, 0.f, 0.f, 0.f, 0.f, 0.f, 0.f};
#pragma unroll
  for (int s = 0; s < SPLITS; ++s) {
    f32x4 v0 = *(const f32x4*)(src + s * PS + lane * 4);
    f32x4 v1 = *(const f32x4*)(src + s * PS + 256 + lane * 4);
#pragma unroll
    for (int r = 0; r < 4; ++r) { x[r] += v0[r]; x[4 + r] += v1[r]; }
  }

  float mx = x[0];
#pragma unroll
  for (int r = 1; r < 8; ++r) mx = fmaxf(mx, x[r]);
#pragma unroll
  for (int off = 32; off >= 1; off >>= 1) mx = fmaxf(mx, __shfl_xor(mx, off));

  float e[8], s = 0.f;
#pragma unroll
  for (int r = 0; r < 8; ++r) { e[r] = expf(x[r] - mx); s += e[r]; }
#pragma unroll
  for (int off = 32; off >= 1; off >>= 1) s += __shfl_xor(s, off);
  const float inv = 1.0f / s;

  __bf16* dst = P + (long)row * NC;
  bf16x4 h0, h1;
#pragma unroll
  for (int r = 0; r < 4; ++r) {
    h0[r] = (__bf16)(e[r] * inv);
    h1[r] = (__bf16)(e[4 + r] * inv);
  }
  *(bf16x4*)(dst + lane * 4) = h0;
  *(bf16x4*)(dst + 256 + lane * 4) = h1;
}

// ---------------------------------------------------------------------------
extern "C" void kernel_launch(void* const* d_in, const int* in_sizes, int n_in,
                              void* d_out, int out_size, void* d_ws,
                              size_t ws_size, hipStream_t stream) {
  const float* img = (const float*)d_in[0];
  const float* txt = (const float*)d_in[1];
  const float* gamma = (const float*)d_in[2];
  float* out = (float*)d_out;

  const size_t MiB = 1024 * 1024;
  // d_out (128 MiB) scratch until gemm_pv overwrites it:
  //   [0, 64 MiB)   kv16  (bf16)
  //   [68, 100 MiB) attnP (2 splits x 16 MiB f32)
  __bf16* kv16 = (__bf16*)d_out;
  float* attnP = (float*)((char*)d_out + 68 * MiB);
  // ws: [0,64 MiB) kvT, [64,72 MiB) P
  __bf16* kvT = (__bf16*)d_ws;
  __bf16* P = (__bf16*)((char*)d_ws + 64 * MiB);

  // 1) kv prep: bf16 row-major + transposed copies
  prep_kv<<<dim3(NHW / 64, NC / 64, NB), 256, 0, stream>>>(txt, kv16, kvT);

  // 2) attn partials = img(f32) * kv16^T  (512x512, K=4096, split 2)
  gemm_qk<QKSPLIT><<<dim3(4, 4, NB * QKSPLIT), 512, 0, stream>>>(
      img, kv16, attnP);

  // 3) P = softmax(sum of partials)
  softmax_rows<QKSPLIT><<<dim3(NB * NC / 4), 256, 0, stream>>>(attnP, P);

  // 4) out = gamma * (kvT * P^T) + img
  gemm_pv<<<dim3(NHW / 128, 4, NB), 512, 0, stream>>>(kvT, P, img, gamma, out);
}

// Round 7
// 221.773 us; speedup vs baseline: 1.0320x; 1.0320x over previous
//
#include <hip/hip_runtime.h>
#include <hip/hip_bf16.h>

// Problem: B=16, C=512, H=W=64 -> HW=4096, fp32.
// attn[b,c,d] = sum_n q[b,c,n]*kv[b,d,n]; P = softmax_d(attn);
// info[b,c,n] = sum_d P[b,c,d]*kv[b,d,n]; out = gamma*info + img.
//
// R7 structure:
//   prep_kv: txt f32 -> kv16 bf16 (in d_out) + kvT bf16 (in ws)
//   gemm_qk: attn partials = img(f32) * kv16^T; dbuf LDS, SINGLE barrier
//            per k-step (write targets the other buffer than compute reads),
//            1-deep early-issue (R5-proven), SPLITK=2
//   softmax: partial-sum + row softmax -> P bf16 (ws)
//   gemm_pv: out = gamma*(kvT * P^T) + img; m97 single-buffer, k-loop fully
//            unrolled with img reads spread 1 f32x4/step (R6-proven)

constexpr int NB = 16;
constexpr int NC = 512;
constexpr int NHW = 4096;
constexpr int QKSPLIT = 2;

typedef float f32x4 __attribute__((ext_vector_type(4)));
typedef __bf16 bf16x4 __attribute__((ext_vector_type(4)));
typedef __bf16 bf16x8 __attribute__((ext_vector_type(8)));

__device__ __forceinline__ void gload16(const void* g, void* l) {
  __builtin_amdgcn_global_load_lds(
      (const __attribute__((address_space(1))) void*)g,
      (__attribute__((address_space(3))) void*)l, 16, 0, 0);
}

// ---------------------------------------------------------------------------
// gemm_qk: D[m][n'] = sum_k A[m][k]*B[n'][k], A f32 (img), B bf16 (kv16).
// Tile 128x128, BK=64, 8 waves (2Mx4N), wave tile 64x32.
// Double-buffered, ONE barrier per k-step:
//   iter tt: loadA(t+1)->regs[4 vmem]; stageB(t+1)->sB[cur^1][2 vmem];
//            compute(cur) [reads buf cur only];
//            vmcnt(2) -> A landed -> writeA(cur^1);
//            vmcnt(0)+lgkmcnt(0) -> B landed + ds_writes done; barrier.
// Safe because writes always target the buffer NOT being read this step,
// and the pre-barrier per-wave drains make buf cur^1 globally ready.
// LDS 64 KiB -> 2 blocks/CU (grid 512 = 2/CU).
// ---------------------------------------------------------------------------
template <int SPLITS>
__global__ __launch_bounds__(512) void gemm_qk(const float* __restrict__ Af,
                                               const __bf16* __restrict__ B,
                                               float* __restrict__ Dp) {
  __shared__ __bf16 sA[2][128 * 64];
  __shared__ __bf16 sB[2][128 * 64];

  const int t = threadIdx.x;
  const int lane = t & 63;
  const int wave = t >> 6;
  const int wr = wave >> 2;
  const int wc = wave & 3;

  // XCD-aware remap (NWG % 8 == 0)
  constexpr int NWG = 16 * NB * SPLITS;
  constexpr int QX = NWG / 8;
  int flat = blockIdx.x + 4 * (blockIdx.y + 4 * blockIdx.z);
  flat = (flat & 7) * QX + (flat >> 3);
  const int bx = flat & 3;
  const int by = (flat >> 2) & 3;
  const int bz = flat >> 4;
  const int batch = bz / SPLITS;
  const int split = bz % SPLITS;

  const int aRow0 = bx * 128;
  const int bRow0 = by * 128;
  constexpr int KSUB = NHW / SPLITS;
  constexpr int NT = KSUB / 64;
  const int kBeg = split * KSUB;

  // B staging (gload_lds): rows wave*16 + i*8 + (lane>>3), src chunk XOR
  const int rl = lane >> 3;
  const int csrc = ((lane & 7) ^ rl) * 8;
  const __bf16* Bbase = B + (long)batch * NC * NHW +
                        (long)(bRow0 + wave * 16 + rl) * NHW + csrc + kBeg;
  const int ldsOff = wave * 16 * 64;

  // A staging (f32 regs): k-cols c4..c4+3, rows rb + 32*i
  const int c4 = (t & 15) * 4;
  const int rb = t >> 4;
  const float* Abase =
      Af + (long)batch * NC * NHW + (long)(aRow0 + rb) * NHW + kBeg + c4;

  f32x4 ra[4];
  auto loadA = [&](int kof) {
#pragma unroll
    for (int i = 0; i < 4; ++i)
      ra[i] = *(const f32x4*)(Abase + kof + (long)(32 * i) * NHW);
  };
  auto writeA = [&](int buf) {
#pragma unroll
    for (int i = 0; i < 4; ++i) {
      const int r = rb + 32 * i;
      const int idx = r * 64 + (c4 ^ ((r & 7) << 3));
      bf16x4 h = {(__bf16)ra[i].x, (__bf16)ra[i].y, (__bf16)ra[i].z,
                  (__bf16)ra[i].w};
      *(bf16x4*)&sA[buf][idx] = h;
    }
  };
  auto stageB = [&](int buf, int kof) {
#pragma unroll
    for (int i = 0; i < 2; ++i)
      gload16(Bbase + kof + (long)(i * 8) * NHW, &sB[buf][ldsOff + i * 8 * 64]);
  };

  f32x4 acc[4][2] = {};
  auto compute_tile = [&](int buf) {
#pragma unroll
    for (int kk = 0; kk < 2; ++kk) {
      const int kb = kk * 32 + ((lane >> 4) << 3);
      bf16x8 af[4], bfr[2];
#pragma unroll
      for (int m = 0; m < 4; ++m) {
        const int r = wr * 64 + m * 16 + (lane & 15);
        af[m] = *(const bf16x8*)&sA[buf][r * 64 + (kb ^ ((r & 7) << 3))];
      }
#pragma unroll
      for (int n = 0; n < 2; ++n) {
        const int r = wc * 32 + n * 16 + (lane & 15);
        bfr[n] = *(const bf16x8*)&sB[buf][r * 64 + (kb ^ ((r & 7) << 3))];
      }
#pragma unroll
      for (int m = 0; m < 4; ++m)
#pragma unroll
        for (int n = 0; n < 2; ++n)
          acc[m][n] = __builtin_amdgcn_mfma_f32_16x16x32_bf16(
              af[m], bfr[n], acc[m][n], 0, 0, 0);
    }
  };

  // prologue: fully stage tile 0 (A loads first, then B gloads)
  loadA(0);      // 4 vmem
  stageB(0, 0);  // 2 vmem
  asm volatile("s_waitcnt vmcnt(2)" ::: "memory");  // A(0) landed
  writeA(0);
  asm volatile("s_waitcnt vmcnt(0) lgkmcnt(0)" ::: "memory");  // B(0) + ds
  __builtin_amdgcn_s_barrier();

  int cur = 0;
#pragma unroll 1
  for (int tt = 0; tt < NT; ++tt) {
    const bool more = (tt + 1) < NT;
    if (more) {
      loadA((tt + 1) * 64);            // 4 vmem -> regs
      stageB(cur ^ 1, (tt + 1) * 64);  // 2 vmem -> other LDS buffer
      asm volatile("" ::: "memory");   // pin issue point before compute
    }
    compute_tile(cur);  // reads buf cur only; ~16 MFMAs of latency cover
    if (more) {
      asm volatile("s_waitcnt vmcnt(2)" ::: "memory");  // A(t+1) landed
      writeA(cur ^ 1);
      asm volatile("s_waitcnt vmcnt(0) lgkmcnt(0)" ::: "memory");  // B + ds
      __builtin_amdgcn_s_barrier();  // single barrier: buf cur^1 ready
      cur ^= 1;
    }
  }

  // epilogue: partial store. C/D layout: col=lane&15, row=(lane>>4)*4+reg
  float* D = Dp + ((long)split * NB + batch) * NC * NC;
  const int m0 = aRow0 + wr * 64;
  const int n0 = bRow0 + wc * 32;
#pragma unroll
  for (int m = 0; m < 4; ++m)
#pragma unroll
    for (int n = 0; n < 2; ++n) {
      const int row0 = m0 + m * 16 + ((lane >> 4) << 2);
      const int col = n0 + n * 16 + (lane & 15);
#pragma unroll
      for (int r = 0; r < 4; ++r)
        D[(long)(row0 + r) * NC + col] = acc[m][n][r];
    }
}

// ---------------------------------------------------------------------------
// gemm_pv: out[b][c][sp] = gamma * sum_d kvT[sp][d]*P[c][d] + img[b][c][sp].
// m97 single-buffer structure; k-loop fully unrolled (8 steps) with one img
// f32x4 load per step (spread traffic; epilogue = compute+store only).
// ---------------------------------------------------------------------------
__global__ __launch_bounds__(512) void gemm_pv(const __bf16* __restrict__ A,
                                               const __bf16* __restrict__ B,
                                               const float* __restrict__ img,
                                               const float* __restrict__ gammap,
                                               float* __restrict__ outp) {
  __shared__ __bf16 sA[128 * 64];
  __shared__ __bf16 sB[128 * 64];

  const int t = threadIdx.x;
  const int lane = t & 63;
  const int wave = t >> 6;
  const int wr = wave >> 2;
  const int wc = wave & 3;

  constexpr int GX = NHW / 128;     // 32
  constexpr int NWG = GX * 4 * NB;  // 2048
  constexpr int QX = NWG / 8;
  int flat = blockIdx.x + GX * (blockIdx.y + 4 * blockIdx.z);
  flat = (flat & 7) * QX + (flat >> 3);
  const int bx = flat % GX;
  const int by = (flat / GX) & 3;
  const int batch = flat / (GX * 4);

  const int aRow0 = bx * 128;
  const int bRow0 = by * 128;

  const int rl = lane >> 3;
  const int csrc = ((lane & 7) ^ rl) * 8;
  const __bf16* Abase =
      A + (long)batch * NHW * NC + (long)(aRow0 + wave * 16 + rl) * NC + csrc;
  const __bf16* Bbase =
      B + (long)batch * NC * NC + (long)(bRow0 + wave * 16 + rl) * NC + csrc;
  const int ldsOff = wave * 16 * 64;

  const long obase = (long)batch * NC * NHW;
  const int sp0 = aRow0 + wr * 64;
  const int ch0 = bRow0 + wc * 32;

  f32x4 acc[4][2] = {};
  f32x4 iv[8];  // img values, loaded one per k-step (static indexing)

#pragma unroll
  for (int step = 0; step < 8; ++step) {
    const int k0 = step * 64;
#pragma unroll
    for (int i = 0; i < 2; ++i) {
      gload16(Abase + k0 + (long)(i * 8) * NC, &sA[ldsOff + i * 8 * 64]);
      gload16(Bbase + k0 + (long)(i * 8) * NC, &sB[ldsOff + i * 8 * 64]);
    }
    {  // spread img read: tile (m,n) = (step>>1, step&1)
      const int m = step >> 1, n = step & 1;
      const int sp = sp0 + m * 16 + ((lane >> 4) << 2);
      const int ch = ch0 + n * 16 + (lane & 15);
      iv[step] = *(const f32x4*)(img + obase + (long)ch * NHW + sp);
    }
    __syncthreads();  // drains vmcnt (gload_lds + img) — m97 structure
#pragma unroll
    for (int kk = 0; kk < 2; ++kk) {
      const int kb = kk * 32 + ((lane >> 4) << 3);
      bf16x8 af[4], bfr[2];
#pragma unroll
      for (int m = 0; m < 4; ++m) {
        const int r = wr * 64 + m * 16 + (lane & 15);
        af[m] = *(const bf16x8*)&sA[r * 64 + (kb ^ ((r & 7) << 3))];
      }
#pragma unroll
      for (int n = 0; n < 2; ++n) {
        const int r = wc * 32 + n * 16 + (lane & 15);
        bfr[n] = *(const bf16x8*)&sB[r * 64 + (kb ^ ((r & 7) << 3))];
      }
#pragma unroll
      for (int m = 0; m < 4; ++m)
#pragma unroll
        for (int n = 0; n < 2; ++n)
          acc[m][n] = __builtin_amdgcn_mfma_f32_16x16x32_bf16(
              af[m], bfr[n], acc[m][n], 0, 0, 0);
    }
    __syncthreads();
  }

  // epilogue: store only
  const float g = gammap[0];
#pragma unroll
  for (int m = 0; m < 4; ++m)
#pragma unroll
    for (int n = 0; n < 2; ++n) {
      const int sp = sp0 + m * 16 + ((lane >> 4) << 2);
      const int ch = ch0 + n * 16 + (lane & 15);
      const long idx = obase + (long)ch * NHW + sp;
      f32x4 ov;
#pragma unroll
      for (int r = 0; r < 4; ++r) ov[r] = g * acc[m][n][r] + iv[m * 2 + n][r];
      *(f32x4*)(outp + idx) = ov;
    }
}

// ---------------------------------------------------------------------------
// prep_kv: kv[b][d][n] f32 -> kv16[b][d][n] bf16 AND kvT[b][n][d] bf16.
// ---------------------------------------------------------------------------
__global__ __launch_bounds__(256) void prep_kv(const float* __restrict__ kv,
                                               __bf16* __restrict__ kv16,
                                               __bf16* __restrict__ kvT) {
  __shared__ __bf16 tile[64 * 68];
  const int t = threadIdx.x;
  const int n0 = blockIdx.x * 64;
  const int d0 = blockIdx.y * 64;
  const long ibase = (long)blockIdx.z * NC * NHW;

  const int nc4 = (t & 15) * 4;
  const int dr0 = t >> 4;
#pragma unroll
  for (int i = 0; i < 4; ++i) {
    const int dr = dr0 + 16 * i;
    f32x4 v = *(const f32x4*)(kv + ibase + (long)(d0 + dr) * NHW + n0 + nc4);
    bf16x4 h = {(__bf16)v.x, (__bf16)v.y, (__bf16)v.z, (__bf16)v.w};
    *(bf16x4*)&tile[dr * 68 + nc4] = h;
    *(bf16x4*)(kv16 + ibase + (long)(d0 + dr) * NHW + n0 + nc4) = h;
  }
  __syncthreads();

  const long obase = (long)blockIdx.z * NHW * NC;
  const int nr = t >> 2;
  const int dc0 = t & 3;
#pragma unroll
  for (int i = 0; i < 2; ++i) {
    const int dc = dc0 + 4 * i;
    bf16x8 pk;
#pragma unroll
    for (int j = 0; j < 8; ++j) pk[j] = tile[(dc * 8 + j) * 68 + nr];
    *(bf16x8*)(kvT + obase + (long)(n0 + nr) * NC + d0 + dc * 8) = pk;
  }
}

// ---------------------------------------------------------------------------
// Row softmax with split-K reduction -> P bf16. One wave per row.
// ---------------------------------------------------------------------------
template <int SPLITS>
__global__ __launch_bounds__(256) void softmax_rows(
    const float* __restrict__ attn, __bf16* __restrict__ P) {
  const int row = blockIdx.x * 4 + (threadIdx.x >> 6);
  const int lane = threadIdx.x & 63;
  const long PS = (long)NB * NC * NC;
  const float* src = attn + (long)row * NC;

  float x[8] = {0.f, 0.f, 0.f, 0.f, 0.f, 0.f, 0.f, 0.f};
#pragma unroll
  for (int s = 0; s < SPLITS; ++s) {
    f32x4 v0 = *(const f32x4*)(src + s * PS + lane * 4);
    f32x4 v1 = *(const f32x4*)(src + s * PS + 256 + lane * 4);
#pragma unroll
    for (int r = 0; r < 4; ++r) { x[r] += v0[r]; x[4 + r] += v1[r]; }
  }

  float mx = x[0];
#pragma unroll
  for (int r = 1; r < 8; ++r) mx = fmaxf(mx, x[r]);
#pragma unroll
  for (int off = 32; off >= 1; off >>= 1) mx = fmaxf(mx, __shfl_xor(mx, off));

  float e[8], s = 0.f;
#pragma unroll
  for (int r = 0; r < 8; ++r) { e[r] = __expf(x[r] - mx); s += e[r]; }
#pragma unroll
  for (int off = 32; off >= 1; off >>= 1) s += __shfl_xor(s, off);
  const float inv = 1.0f / s;

  __bf16* dst = P + (long)row * NC;
  bf16x4 h0, h1;
#pragma unroll
  for (int r = 0; r < 4; ++r) {
    h0[r] = (__bf16)(e[r] * inv);
    h1[r] = (__bf16)(e[4 + r] * inv);
  }
  *(bf16x4*)(dst + lane * 4) = h0;
  *(bf16x4*)(dst + 256 + lane * 4) = h1;
}

// ---------------------------------------------------------------------------
extern "C" void kernel_launch(void* const* d_in, const int* in_sizes, int n_in,
                              void* d_out, int out_size, void* d_ws,
                              size_t ws_size, hipStream_t stream) {
  const float* img = (const float*)d_in[0];
  const float* txt = (const float*)d_in[1];
  const float* gamma = (const float*)d_in[2];
  float* out = (float*)d_out;

  const size_t MiB = 1024 * 1024;
  // d_out (128 MiB) scratch until gemm_pv overwrites it:
  //   [0, 64 MiB)   kv16  (bf16)
  //   [68, 100 MiB) attnP (2 splits x 16 MiB f32)
  __bf16* kv16 = (__bf16*)d_out;
  float* attnP = (float*)((char*)d_out + 68 * MiB);
  // ws: [0,64 MiB) kvT, [64,72 MiB) P
  __bf16* kvT = (__bf16*)d_ws;
  __bf16* P = (__bf16*)((char*)d_ws + 64 * MiB);

  // 1) kv prep: bf16 row-major + transposed copies
  prep_kv<<<dim3(NHW / 64, NC / 64, NB), 256, 0, stream>>>(txt, kv16, kvT);

  // 2) attn partials = img(f32) * kv16^T  (512x512, K=4096, split 2)
  gemm_qk<QKSPLIT><<<dim3(4, 4, NB * QKSPLIT), 512, 0, stream>>>(
      img, kv16, attnP);

  // 3) P = softmax(sum of partials)
  softmax_rows<QKSPLIT><<<dim3(NB * NC / 4), 256, 0, stream>>>(attnP, P);

  // 4) out = gamma * (kvT * P^T) + img
  gemm_pv<<<dim3(NHW / 128, 4, NB), 512, 0, stream>>>(kvT, P, img, gamma, out);
}